// Round 1
// baseline (546.259 us; speedup 1.0000x reference)
//
#include <hip/hip_runtime.h>
#include <hip/hip_bf16.h>
#include <math.h>

// ---------------------------------------------------------------------------
// AudioVQMix: wave VQ (1024 codes, D=80) + mfcc transform (cos-matmul 80->38,
// l2norm) + mfcc VQ (256 codes, D=38) + losses + perplexities.
// Output layout (float32): [0 .. 131071] encodings (out[2r]=wave_idx,
// out[2r+1]=mfcc_idx+1024), then wave_ppl, wave_loss, mfcc_ppl, mfcc_loss.
// ---------------------------------------------------------------------------

#define NROWS 65536        // 16 * 4096
#define DW    80
#define KW    1024
#define DM    38
#define DMP   40           // padded to float4 multiple
#define KM    256

// workspace layout (bytes)
//   0     : counts_w (1024 i32)
//   4096  : counts_m (256 i32)
//   5120  : sums (2 f32: wave_loss_sum, mfcc_loss_sum)
//   5632  : cn_w (1024 f32)
//   9728  : cn_m (256 f32)
//   10752 : costab (80*40 f32, zero-padded cols 38,39)

__global__ __launch_bounds__(256) void prep_kernel(
    const float* __restrict__ cbw, const float* __restrict__ cbm,
    int* __restrict__ counts_w, int* __restrict__ counts_m,
    float* __restrict__ sums, float* __restrict__ cn_w,
    float* __restrict__ cn_m, float* __restrict__ costab)
{
    int idx = blockIdx.x * 256 + threadIdx.x;
    if (idx < KW) {
        counts_w[idx] = 0;
        const float* p = cbw + (size_t)idx * DW;
        float s = 0.f;
        for (int i = 0; i < DW; ++i) s = fmaf(p[i], p[i], s);
        cn_w[idx] = s;
    } else if (idx < KW + KM) {
        int i = idx - KW;
        counts_m[i] = 0;
        const float* p = cbm + (size_t)i * DM;
        float s = 0.f;
        for (int j = 0; j < DM; ++j) s = fmaf(p[j], p[j], s);
        cn_m[i] = s;
    } else if (idx < KW + KM + DW * DMP) {
        int t = idx - (KW + KM);
        int d = t / DMP, j = t % DMP;
        double v = (j < DM)
            ? cos(2.0 * 3.14159265358979323846 * (double)((j + 2) * d) / 80.0)
            : 0.0;
        costab[t] = (float)v;
    } else if (idx == KW + KM + DW * DMP)     sums[0] = 0.f;
    else if (idx == KW + KM + DW * DMP + 1)   sums[1] = 0.f;
}

// Wave VQ: 64 rows/block, 4 threads per row (each scans 16 codes per 64-code
// chunk). x row held in 80 VGPRs; codebook chunk staged in LDS, read as
// wave-uniform broadcast float4s (conflict-free).
__global__ __launch_bounds__(256) void wave_vq_kernel(
    const float* __restrict__ X, const float* __restrict__ cb,
    const float* __restrict__ cn, float* __restrict__ out,
    int* __restrict__ counts, float* __restrict__ loss_sum)
{
    __shared__ float c_lds[64 * DW];
    __shared__ float cn_lds[64];
    __shared__ float red_d[256];
    __shared__ int   red_i[256];

    const int tid = threadIdx.x;
    const int rl  = tid & 63;      // row within block
    const int q   = tid >> 6;      // code-quarter (one per wave)
    const size_t r = (size_t)blockIdx.x * 64 + rl;

    float x[DW];
    const float4* xp = (const float4*)(X + r * DW);
    #pragma unroll
    for (int i = 0; i < DW / 4; ++i) {
        float4 v = xp[i];
        x[4*i+0] = v.x; x[4*i+1] = v.y; x[4*i+2] = v.z; x[4*i+3] = v.w;
    }

    float best = 3.4e38f; int bidx = 0;

    for (int ch = 0; ch < KW / 64; ++ch) {
        __syncthreads();
        const float4* src = (const float4*)(cb + (size_t)ch * 64 * DW);
        float4* dst = (float4*)c_lds;
        #pragma unroll
        for (int i = 0; i < 5; ++i) dst[tid + 256 * i] = src[tid + 256 * i];
        if (tid < 64) cn_lds[tid] = cn[ch * 64 + tid];
        __syncthreads();

        for (int g = 0; g < 4; ++g) {
            const int c0 = q * 16 + g * 4;     // wave-uniform
            const float* cr0 = &c_lds[(c0 + 0) * DW];
            const float* cr1 = &c_lds[(c0 + 1) * DW];
            const float* cr2 = &c_lds[(c0 + 2) * DW];
            const float* cr3 = &c_lds[(c0 + 3) * DW];
            float a0 = 0.f, a1 = 0.f, a2 = 0.f, a3 = 0.f;
            #pragma unroll
            for (int k4 = 0; k4 < DW / 4; ++k4) {
                float4 v0 = *(const float4*)(cr0 + 4 * k4);
                float4 v1 = *(const float4*)(cr1 + 4 * k4);
                float4 v2 = *(const float4*)(cr2 + 4 * k4);
                float4 v3 = *(const float4*)(cr3 + 4 * k4);
                a0 = fmaf(x[4*k4+0], v0.x, a0); a0 = fmaf(x[4*k4+1], v0.y, a0);
                a0 = fmaf(x[4*k4+2], v0.z, a0); a0 = fmaf(x[4*k4+3], v0.w, a0);
                a1 = fmaf(x[4*k4+0], v1.x, a1); a1 = fmaf(x[4*k4+1], v1.y, a1);
                a1 = fmaf(x[4*k4+2], v1.z, a1); a1 = fmaf(x[4*k4+3], v1.w, a1);
                a2 = fmaf(x[4*k4+0], v2.x, a2); a2 = fmaf(x[4*k4+1], v2.y, a2);
                a2 = fmaf(x[4*k4+2], v2.z, a2); a2 = fmaf(x[4*k4+3], v2.w, a2);
                a3 = fmaf(x[4*k4+0], v3.x, a3); a3 = fmaf(x[4*k4+1], v3.y, a3);
                a3 = fmaf(x[4*k4+2], v3.z, a3); a3 = fmaf(x[4*k4+3], v3.w, a3);
            }
            const int cbase = ch * 64 + c0;
            float d0 = cn_lds[c0 + 0] - 2.0f * a0;
            float d1 = cn_lds[c0 + 1] - 2.0f * a1;
            float d2 = cn_lds[c0 + 2] - 2.0f * a2;
            float d3 = cn_lds[c0 + 3] - 2.0f * a3;
            if (d0 < best) { best = d0; bidx = cbase + 0; }
            if (d1 < best) { best = d1; bidx = cbase + 1; }
            if (d2 < best) { best = d2; bidx = cbase + 2; }
            if (d3 < best) { best = d3; bidx = cbase + 3; }
        }
    }

    __syncthreads();
    red_d[tid] = best; red_i[tid] = bidx;
    __syncthreads();
    if (tid < 64) {
        #pragma unroll
        for (int qq = 1; qq < 4; ++qq) {
            float d2 = red_d[qq * 64 + tid];
            int   i2 = red_i[qq * 64 + tid];
            if (d2 < best || (d2 == best && i2 < bidx)) { best = d2; bidx = i2; }
        }
        out[2 * r] = (float)bidx;
        atomicAdd(&counts[bidx], 1);
        // loss contribution: sum_d (x - q)^2
        const float* qp = cb + (size_t)bidx * DW;
        float s = 0.f;
        #pragma unroll
        for (int i = 0; i < DW; ++i) { float df = x[i] - qp[i]; s = fmaf(df, df, s); }
        #pragma unroll
        for (int off = 32; off >= 1; off >>= 1) s += __shfl_xor(s, off, 64);
        if (tid == 0) atomicAdd(loss_sum, s);
    }
}

// MFCC: per-thread row transform (80 -> 38 cosine matmul, l2norm; the first
// l2norm cancels exactly), then VQ against all 256 codes staged in LDS.
__global__ __launch_bounds__(256) void mfcc_vq_kernel(
    const float* __restrict__ X, const float* __restrict__ cb,
    const float* __restrict__ cn, const float* __restrict__ costab,
    float* __restrict__ out, int* __restrict__ counts,
    float* __restrict__ loss_sum)
{
    __shared__ float cos_lds[DW * DMP];     // 12.8 KB
    __shared__ float cb_lds[KM * DMP];      // 40 KB (zero-padded cols 38,39)
    __shared__ float cn_lds[KM];

    const int tid = threadIdx.x;
    for (int i = tid; i < DW * DMP; i += 256) cos_lds[i] = costab[i];
    {
        #pragma unroll
        for (int j = 0; j < DM; ++j) cb_lds[tid * DMP + j] = cb[tid * DM + j];
        cb_lds[tid * DMP + 38] = 0.f;
        cb_lds[tid * DMP + 39] = 0.f;
        cn_lds[tid] = cn[tid];
    }
    __syncthreads();

    const size_t r = (size_t)blockIdx.x * 256 + tid;
    const float* xp = X + r * DW;

    float xm[DMP];
    #pragma unroll
    for (int j = 0; j < DMP; ++j) xm[j] = 0.f;

    for (int d = 0; d < DW; ++d) {
        float xd = xp[d];
        const float4* crow = (const float4*)&cos_lds[d * DMP];
        #pragma unroll
        for (int k4 = 0; k4 < DMP / 4; ++k4) {
            float4 v = crow[k4];
            xm[4*k4+0] = fmaf(xd, v.x, xm[4*k4+0]);
            xm[4*k4+1] = fmaf(xd, v.y, xm[4*k4+1]);
            xm[4*k4+2] = fmaf(xd, v.z, xm[4*k4+2]);
            xm[4*k4+3] = fmaf(xd, v.w, xm[4*k4+3]);
        }
    }
    // l2 normalize (38 live elements; pads stay 0)
    float n2 = 0.f;
    #pragma unroll
    for (int j = 0; j < DM; ++j) n2 = fmaf(xm[j], xm[j], n2);
    float inv = 1.0f / fmaxf(sqrtf(n2), 1e-12f);
    #pragma unroll
    for (int j = 0; j < DM; ++j) xm[j] *= inv;

    float best = 3.4e38f; int bidx = 0;
    for (int g = 0; g < KM / 4; ++g) {
        const float* cr0 = &cb_lds[(4*g + 0) * DMP];
        const float* cr1 = &cb_lds[(4*g + 1) * DMP];
        const float* cr2 = &cb_lds[(4*g + 2) * DMP];
        const float* cr3 = &cb_lds[(4*g + 3) * DMP];
        float a0 = 0.f, a1 = 0.f, a2 = 0.f, a3 = 0.f;
        #pragma unroll
        for (int k4 = 0; k4 < DMP / 4; ++k4) {
            float4 v0 = *(const float4*)(cr0 + 4 * k4);
            float4 v1 = *(const float4*)(cr1 + 4 * k4);
            float4 v2 = *(const float4*)(cr2 + 4 * k4);
            float4 v3 = *(const float4*)(cr3 + 4 * k4);
            a0 = fmaf(xm[4*k4+0], v0.x, a0); a0 = fmaf(xm[4*k4+1], v0.y, a0);
            a0 = fmaf(xm[4*k4+2], v0.z, a0); a0 = fmaf(xm[4*k4+3], v0.w, a0);
            a1 = fmaf(xm[4*k4+0], v1.x, a1); a1 = fmaf(xm[4*k4+1], v1.y, a1);
            a1 = fmaf(xm[4*k4+2], v1.z, a1); a1 = fmaf(xm[4*k4+3], v1.w, a1);
            a2 = fmaf(xm[4*k4+0], v2.x, a2); a2 = fmaf(xm[4*k4+1], v2.y, a2);
            a2 = fmaf(xm[4*k4+2], v2.z, a2); a2 = fmaf(xm[4*k4+3], v2.w, a2);
            a3 = fmaf(xm[4*k4+0], v3.x, a3); a3 = fmaf(xm[4*k4+1], v3.y, a3);
            a3 = fmaf(xm[4*k4+2], v3.z, a3); a3 = fmaf(xm[4*k4+3], v3.w, a3);
        }
        const int cbase = 4 * g;
        float d0 = cn_lds[cbase + 0] - 2.0f * a0;
        float d1 = cn_lds[cbase + 1] - 2.0f * a1;
        float d2 = cn_lds[cbase + 2] - 2.0f * a2;
        float d3 = cn_lds[cbase + 3] - 2.0f * a3;
        if (d0 < best) { best = d0; bidx = cbase + 0; }
        if (d1 < best) { best = d1; bidx = cbase + 1; }
        if (d2 < best) { best = d2; bidx = cbase + 2; }
        if (d3 < best) { best = d3; bidx = cbase + 3; }
    }

    out[2 * r + 1] = (float)(bidx + KW);
    atomicAdd(&counts[bidx], 1);
    const float* qp = cb + (size_t)bidx * DM;
    float s = 0.f;
    #pragma unroll
    for (int j = 0; j < DM; ++j) { float df = xm[j] - qp[j]; s = fmaf(df, df, s); }
    #pragma unroll
    for (int off = 32; off >= 1; off >>= 1) s += __shfl_xor(s, off, 64);
    if ((tid & 63) == 0) atomicAdd(loss_sum, s);
}

__global__ __launch_bounds__(256) void finalize_kernel(
    const int* __restrict__ counts_w, const int* __restrict__ counts_m,
    const float* __restrict__ sums, float* __restrict__ out)
{
    __shared__ float red[4];
    const int tid = threadIdx.x;
    const bool wv = (blockIdx.x == 0);
    const int K = wv ? KW : KM;
    const int* c = wv ? counts_w : counts_m;
    float s = 0.f;
    for (int i = tid; i < K; i += 256) {
        float p = (float)c[i] * (1.0f / 65536.0f);
        s += p * logf(p + 1e-10f);
    }
    #pragma unroll
    for (int off = 32; off >= 1; off >>= 1) s += __shfl_xor(s, off, 64);
    if ((tid & 63) == 0) red[tid >> 6] = s;
    __syncthreads();
    if (tid == 0) {
        float t = red[0] + red[1] + red[2] + red[3];
        float ppl = expf(-t);
        float denom = wv ? (float)(NROWS * DW) : (float)(NROWS * DM);
        int base = 2 * NROWS + (wv ? 0 : 2);
        out[base]     = ppl;
        out[base + 1] = 1.25f * sums[wv ? 0 : 1] / denom;
    }
}

extern "C" void kernel_launch(void* const* d_in, const int* in_sizes, int n_in,
                              void* d_out, int out_size, void* d_ws, size_t ws_size,
                              hipStream_t stream) {
    const float* X   = (const float*)d_in[0];
    const float* cbw = (const float*)d_in[1];
    const float* cbm = (const float*)d_in[2];
    float* out = (float*)d_out;

    char* ws = (char*)d_ws;
    int*   counts_w = (int*)(ws + 0);
    int*   counts_m = (int*)(ws + 4096);
    float* sums     = (float*)(ws + 5120);
    float* cn_w     = (float*)(ws + 5632);
    float* cn_m     = (float*)(ws + 9728);
    float* costab   = (float*)(ws + 10752);

    prep_kernel<<<18, 256, 0, stream>>>(cbw, cbm, counts_w, counts_m, sums,
                                        cn_w, cn_m, costab);
    wave_vq_kernel<<<NROWS / 64, 256, 0, stream>>>(X, cbw, cn_w, out,
                                                   counts_w, sums + 0);
    mfcc_vq_kernel<<<NROWS / 256, 256, 0, stream>>>(X, cbm, cn_m, costab, out,
                                                    counts_m, sums + 1);
    finalize_kernel<<<2, 256, 0, stream>>>(counts_w, counts_m, sums, out);
}